// Round 3
// baseline (563.418 us; speedup 1.0000x reference)
//
#include <hip/hip_runtime.h>
#include <hip/hip_bf16.h>

typedef __hip_bfloat16 bf16;
typedef __attribute__((ext_vector_type(8))) short short8;
typedef __attribute__((ext_vector_type(4))) float f32x4;

#define AS1 __attribute__((address_space(1)))
#define AS3 __attribute__((address_space(3)))

__device__ __forceinline__ void gload_lds16(const bf16* gp, bf16* lp) {
  __builtin_amdgcn_global_load_lds((const AS1 void*)gp, (AS3 void*)lp, 16, 0, 0);
}

__device__ __forceinline__ void store_c(bf16* C, size_t idx, float v) { C[idx] = __float2bfloat16(v); }
__device__ __forceinline__ void store_c(float* C, size_t idx, float v) { C[idx] = v; }

// ---------------------------------------------------------------------------
// fp32 -> bf16 elementwise convert (n multiple of 1024)
// ---------------------------------------------------------------------------
__global__ void cvt_f32_bf16(const float* __restrict__ in, bf16* __restrict__ out) {
  const int i = (blockIdx.x * 256 + threadIdx.x) * 4;
  const float4 v = *(const float4*)(in + i);
  out[i + 0] = __float2bfloat16(v.x);
  out[i + 1] = __float2bfloat16(v.y);
  out[i + 2] = __float2bfloat16(v.z);
  out[i + 3] = __float2bfloat16(v.w);
}

// ---------------------------------------------------------------------------
// Generic bf16 GEMM, C = A @ B with B supplied transposed (Bt[N][K]).
// m97 structure: 128x128 tile, BK=32, global_load_lds width-16, 16x16x32 MFMA.
// Epilogue column mapping:
//   mode 0: g = colbase + n
//   mode 1: g = (n>>6)*128 + colbase + (n&63)          (H*64 -> [H,128] slot)
//   mode 2: g = ((n>>6)&15)*128 + (n>>10)*64 + (n&63)  (2*H*64 concat -> [H,128])
// ---------------------------------------------------------------------------
template <typename CT>
__global__ void gemm_bt(const bf16* __restrict__ A, int lda,
                        const bf16* __restrict__ Bt,
                        CT* __restrict__ C, int ldc,
                        int K, int mode, int colbase)
{
  __shared__ __align__(16) bf16 As[128 * 32];
  __shared__ __align__(16) bf16 Bs[128 * 32];
  const int tid  = threadIdx.x;
  const int wave = tid >> 6, lane = tid & 63;
  const int quad = lane >> 4, l16 = lane & 15;
  const int m0 = blockIdx.y * 128, n0 = blockIdx.x * 128;
  const int wm = (wave >> 1) * 64, wn = (wave & 1) * 64;

  f32x4 acc[4][4];
  for (int i = 0; i < 4; ++i)
    for (int j = 0; j < 4; ++j) acc[i][j] = (f32x4){0.f, 0.f, 0.f, 0.f};

  const int r1  = tid >> 2;          // staging row (0..63), +64 for second seg
  const int ks1 = (tid & 3) * 8;     // k-offset in elements

  for (int k0 = 0; k0 < K; k0 += 32) {
    gload_lds16(A  + (size_t)(m0 + r1)      * lda + k0 + ks1, &As[tid * 8]);
    gload_lds16(A  + (size_t)(m0 + r1 + 64) * lda + k0 + ks1, &As[(tid + 256) * 8]);
    gload_lds16(Bt + (size_t)(n0 + r1)      * K   + k0 + ks1, &Bs[tid * 8]);
    gload_lds16(Bt + (size_t)(n0 + r1 + 64) * K   + k0 + ks1, &Bs[(tid + 256) * 8]);
    __syncthreads();

    short8 af[4], bf_[4];
    for (int mt = 0; mt < 4; ++mt)
      af[mt] = *(const short8*)&As[(wm + mt * 16 + l16) * 32 + quad * 8];
    for (int nt = 0; nt < 4; ++nt)
      bf_[nt] = *(const short8*)&Bs[(wn + nt * 16 + l16) * 32 + quad * 8];
    for (int mt = 0; mt < 4; ++mt)
      for (int nt = 0; nt < 4; ++nt)
        acc[mt][nt] = __builtin_amdgcn_mfma_f32_16x16x32_bf16(af[mt], bf_[nt], acc[mt][nt], 0, 0, 0);
    __syncthreads();
  }

  for (int mt = 0; mt < 4; ++mt) {
    const int row = m0 + wm + mt * 16 + quad * 4;
    for (int nt = 0; nt < 4; ++nt) {
      const int cn = n0 + wn + nt * 16 + l16;
      int g;
      if (mode == 0)      g = colbase + cn;
      else if (mode == 1) g = ((cn >> 6) << 7) + colbase + (cn & 63);
      else                g = (((cn >> 6) & 15) << 7) + ((cn >> 10) << 6) + (cn & 63);
      const f32x4 v = acc[mt][nt];
      for (int r = 0; r < 4; ++r)
        store_c(C, (size_t)(row + r) * ldc + g, v[r]);
    }
  }
}

// ---------------------------------------------------------------------------
// fp32 -> bf16 transposing copy: out[C][R] = (bf16) in[R][C]
// ---------------------------------------------------------------------------
__global__ void transpose_f32_bf16(const float* __restrict__ in, bf16* __restrict__ out,
                                   int R, int C)
{
  __shared__ bf16 t[32][33];
  const int c0 = blockIdx.x * 32, r0 = blockIdx.y * 32;
  const int tx = threadIdx.x, ty = threadIdx.y;
  for (int i = 0; i < 4; ++i)
    t[ty + 8 * i][tx] = __float2bfloat16(in[(size_t)(r0 + ty + 8 * i) * C + c0 + tx]);
  __syncthreads();
  for (int i = 0; i < 4; ++i)
    out[(size_t)(c0 + ty + 8 * i) * R + r0 + tx] = t[tx][ty + 8 * i];
}

// ---------------------------------------------------------------------------
// RoPE in place on q/k [B,S,H,128], rope half = dims 64..127, dim=64 (32 pairs)
// ---------------------------------------------------------------------------
__global__ void rope_kernel(bf16* __restrict__ q, bf16* __restrict__ k)
{
  const int idx = blockIdx.x * 256 + threadIdx.x;   // B*S*H*32 threads
  const int i = idx & 31;
  const int h = (idx >> 5) & 15;
  const int s = (idx >> 9) & 2047;
  const int b = idx >> 20;
  const size_t off = ((size_t)(b * 2048 + s)) * 2048 + h * 128 + 64;
  const float inv = powf(10000.0f, -(float)i * (1.0f / 32.0f));
  const float ang = (float)s * inv;
  const float cs = cosf(ang), sn = sinf(ang);
  {
    bf16* p = q + off;
    const float x1 = __bfloat162float(p[i]);
    const float x2 = __bfloat162float(p[i + 32]);
    p[i]      = __float2bfloat16(x1 * cs - x2 * sn);
    p[i + 32] = __float2bfloat16(x2 * cs + x1 * sn);
  }
  {
    bf16* p = k + off;
    const float x1 = __bfloat162float(p[i]);
    const float x2 = __bfloat162float(p[i + 32]);
    p[i]      = __float2bfloat16(x1 * cs - x2 * sn);
    p[i + 32] = __float2bfloat16(x2 * cs + x1 * sn);
  }
}

// ---------------------------------------------------------------------------
// Flash attention (causal), bf16 MFMA. 64-row Q-tile per block, 64-key tiles.
// grid = (S/64, B*H), block = 256 (4 waves; wave w owns rows q0+w*16..+15).
// ---------------------------------------------------------------------------
__global__ void attn_kernel(const bf16* __restrict__ Q, const bf16* __restrict__ Kf,
                            const bf16* __restrict__ V, bf16* __restrict__ Y)
{
  constexpr int SEQ = 2048, ROWP = 2048, D = 128;
  __shared__ __align__(16) bf16 Ks[64][136];   // K tile, +8 pad
  __shared__ __align__(16) bf16 Vt[128][72];   // V tile transposed [d][key], +8 pad
  __shared__ __align__(16) bf16 Ps[4][16][72]; // per-wave P round-trip
  const int tid  = threadIdx.x;
  const int wave = tid >> 6, lane = tid & 63;
  const int quad = lane >> 4, l16 = lane & 15;
  const int b = blockIdx.y >> 4, h = blockIdx.y & 15;
  const int q0 = blockIdx.x * 64;
  const size_t base = ((size_t)b * SEQ) * ROWP + h * D;

  // Q fragments (A-layout: m=lane&15, k=quad*8+j), held for the whole kernel
  short8 qf[4];
  {
    const int qrow = q0 + wave * 16 + l16;
    const bf16* qp = Q + base + (size_t)qrow * ROWP + quad * 8;
    for (int kc = 0; kc < 4; ++kc) qf[kc] = *(const short8*)(qp + kc * 32);
  }
  f32x4 o[8];
  for (int i = 0; i < 8; ++i) o[i] = (f32x4){0, 0, 0, 0};
  float mrow[4] = {-1e30f, -1e30f, -1e30f, -1e30f};
  float lrow[4] = {0, 0, 0, 0};
  const float scale = 0.08838834764831845f;  // 1/sqrt(128)
  const float LOG2E = 1.44269504088896f;
  const int row0q = q0 + wave * 16 + quad * 4;

  const int ktiles = blockIdx.x + 1;
  for (int it = 0; it < ktiles; ++it) {
    const int k0 = it * 64;
    // stage K tile (coalesced 16B)
    for (int i = 0; i < 4; ++i) {
      const int s = tid + i * 256;
      const int row = s >> 4, c8 = (s & 15) * 8;
      *(short8*)&Ks[row][c8] = *(const short8*)(Kf + base + (size_t)(k0 + row) * ROWP + c8);
    }
    // stage V tile transposed
    {
      const int key = tid & 63, dg = tid >> 6;
      const bf16* vp = V + base + (size_t)(k0 + key) * ROWP + dg * 32;
      for (int i = 0; i < 4; ++i) {
        const short8 vv = *(const short8*)(vp + i * 8);
        const bf16* e = (const bf16*)&vv;
        for (int j = 0; j < 8; ++j) Vt[dg * 32 + i * 8 + j][key] = e[j];
      }
    }
    __syncthreads();

    // S = Q K^T for 4 x 16-key subtiles
    f32x4 sf[4];
    for (int kt = 0; kt < 4; ++kt) {
      f32x4 a = (f32x4){0, 0, 0, 0};
      for (int kc = 0; kc < 4; ++kc) {
        const short8 bfr = *(const short8*)&Ks[kt * 16 + l16][kc * 32 + quad * 8];
        a = __builtin_amdgcn_mfma_f32_16x16x32_bf16(qf[kc], bfr, a, 0, 0, 0);
      }
      sf[kt] = a;
    }
    // scale + causal mask (only the diagonal tile needs masking)
    if (it == ktiles - 1) {
      for (int kt = 0; kt < 4; ++kt) {
        const int col = k0 + kt * 16 + l16;
        for (int r = 0; r < 4; ++r) {
          const float v = sf[kt][r] * scale;
          sf[kt][r] = (col > row0q + r) ? -1e30f : v;
        }
      }
    } else {
      for (int kt = 0; kt < 4; ++kt)
        for (int r = 0; r < 4; ++r) sf[kt][r] *= scale;
    }
    // online softmax row stats (reduce across 16 lanes of the quad)
    float mt[4];
    for (int r = 0; r < 4; ++r)
      mt[r] = fmaxf(fmaxf(sf[0][r], sf[1][r]), fmaxf(sf[2][r], sf[3][r]));
    for (int off = 8; off >= 1; off >>= 1)
      for (int r = 0; r < 4; ++r) mt[r] = fmaxf(mt[r], __shfl_xor(mt[r], off, 16));
    float alpha[4];
    for (int r = 0; r < 4; ++r) {
      const float mn = fmaxf(mrow[r], mt[r]);
      alpha[r] = exp2f((mrow[r] - mn) * LOG2E);
      mrow[r] = mn;
    }
    float rs[4] = {0, 0, 0, 0};
    for (int kt = 0; kt < 4; ++kt)
      for (int r = 0; r < 4; ++r) {
        const float p = exp2f((sf[kt][r] - mrow[r]) * LOG2E);
        sf[kt][r] = p; rs[r] += p;
      }
    for (int off = 8; off >= 1; off >>= 1)
      for (int r = 0; r < 4; ++r) rs[r] += __shfl_xor(rs[r], off, 16);
    for (int r = 0; r < 4; ++r) lrow[r] = lrow[r] * alpha[r] + rs[r];
    for (int i = 0; i < 8; ++i)
      for (int r = 0; r < 4; ++r) o[i][r] *= alpha[r];
    // P: C-layout -> A-layout via per-wave LDS round trip
    for (int kt = 0; kt < 4; ++kt)
      for (int r = 0; r < 4; ++r)
        Ps[wave][quad * 4 + r][kt * 16 + l16] = __float2bfloat16(sf[kt][r]);
    __syncthreads();   // orders Ps writes before Ps vector reads
    // O += P V
    for (int kc = 0; kc < 2; ++kc) {
      const short8 ap = *(const short8*)&Ps[wave][l16][kc * 32 + quad * 8];
      for (int dt = 0; dt < 8; ++dt) {
        const short8 vb = *(const short8*)&Vt[dt * 16 + l16][kc * 32 + quad * 8];
        o[dt] = __builtin_amdgcn_mfma_f32_16x16x32_bf16(ap, vb, o[dt], 0, 0, 0);
      }
    }
    __syncthreads();
  }
  for (int r = 0; r < 4; ++r) {
    const float inv = 1.0f / lrow[r];
    for (int dt = 0; dt < 8; ++dt)
      Y[base + (size_t)(row0q + r) * ROWP + dt * 16 + l16] = __float2bfloat16(o[dt][r] * inv);
  }
}

// ---------------------------------------------------------------------------
extern "C" void kernel_launch(void* const* d_in, const int* in_sizes, int n_in,
                              void* d_out, int out_size, void* d_ws, size_t ws_size,
                              hipStream_t stream)
{
  // Inputs are float32 (per the reference); we convert to bf16 once and run
  // the whole pipeline in bf16 (f32 accumulate), storing the final GEMM in f32.
  const float* x      = (const float*)d_in[0];
  const float* Wkvd   = (const float*)d_in[1];
  const float* Wqd    = (const float*)d_in[2];
  const float* Wku    = (const float*)d_in[3];
  const float* Wqu    = (const float*)d_in[4];
  const float* Wvu    = (const float*)d_in[5];
  const float* Wropek = (const float*)d_in[6];
  const float* Wropeq = (const float*)d_in[7];
  const float* Wo     = (const float*)d_in[8];

  char* ws = (char*)d_ws;
  size_t off = 0;
  auto alloc = [&](size_t elems) {
    bf16* p = (bf16*)(ws + off);
    off += ((elems * sizeof(bf16) + 255) & ~(size_t)255);
    return p;
  };
  // Region A (dead after gemm5) -- ybuf (16 MB) aliases its first 16 MB.
  bf16* wtKVQ  = alloc((size_t)1024 * 2048); // rows 0..511 = Wkvd^T, 512..1023 = Wqd^T
  bf16* wtQcat = alloc((size_t)2048 * 512);  // rows 0..1023 = Wqu^T, 1024..2047 = Wropeq^T
  bf16* wt_ku  = alloc((size_t)1024 * 512);
  bf16* wt_vu  = alloc((size_t)2048 * 512);
  bf16* wt_rk  = alloc((size_t)1024 * 2048);
  bf16* latcat = alloc((size_t)4096 * 1024); // cols 0..511 kv_latent, 512..1023 q_latent
  // end of region A (21 MB)
  bf16* xbf    = alloc((size_t)4096 * 2048);
  bf16* wt_o   = alloc((size_t)2048 * 2048);
  bf16* qfull  = alloc((size_t)4096 * 2048);
  bf16* kfull  = alloc((size_t)4096 * 2048);
  bf16* ybuf   = (bf16*)ws;                  // aliases region A (dead by then)
  bf16* vfull  = (bf16*)d_out;               // d_out is 32 MB fp32; v uses 16 MB,
                                             // final GEMM overwrites all of it
  (void)ws_size; (void)in_sizes; (void)n_in; (void)out_size;

  cvt_f32_bf16<<<8192, 256, 0, stream>>>(x, xbf);   // 4096*2048 elems

  const dim3 tb(32, 8);
  transpose_f32_bf16<<<dim3(16, 64),  tb, 0, stream>>>(Wkvd,   wtKVQ,                2048, 512);
  transpose_f32_bf16<<<dim3(16, 64),  tb, 0, stream>>>(Wqd,    wtKVQ + 512 * 2048,   2048, 512);
  transpose_f32_bf16<<<dim3(32, 16),  tb, 0, stream>>>(Wqu,    wtQcat,               512, 1024);
  transpose_f32_bf16<<<dim3(32, 16),  tb, 0, stream>>>(Wropeq, wtQcat + 1024 * 512,  512, 1024);
  transpose_f32_bf16<<<dim3(32, 16),  tb, 0, stream>>>(Wku,    wt_ku,                512, 1024);
  transpose_f32_bf16<<<dim3(64, 16),  tb, 0, stream>>>(Wvu,    wt_vu,                512, 2048);
  transpose_f32_bf16<<<dim3(32, 64),  tb, 0, stream>>>(Wropek, wt_rk,                2048, 1024);
  transpose_f32_bf16<<<dim3(64, 64),  tb, 0, stream>>>(Wo,     wt_o,                 2048, 2048);

  // latcat = x @ [W_kv_d | W_q_d]            M=4096 N=1024 K=2048
  gemm_bt<<<dim3(8, 32), 256, 0, stream>>>(xbf, 2048, wtKVQ, latcat, 1024, 2048, 0, 0);
  // k_nope: kv_latent @ W_k_u -> kfull[:, h*128+0..63]
  gemm_bt<<<dim3(8, 32), 256, 0, stream>>>(latcat, 1024, wt_ku, kfull, 2048, 512, 1, 0);
  // v: kv_latent @ W_v_u -> vfull (natural [B,S,H,128]), lives in d_out
  gemm_bt<<<dim3(16, 32), 256, 0, stream>>>(latcat, 1024, wt_vu, vfull, 2048, 512, 0, 0);
  // q: q_latent @ [W_q_u | W_rope_q] -> qfull interleaved
  gemm_bt<<<dim3(16, 32), 256, 0, stream>>>(latcat + 512, 1024, wtQcat, qfull, 2048, 512, 2, 0);
  // k_rope: x @ W_rope_k -> kfull[:, h*128+64..127]
  gemm_bt<<<dim3(8, 32), 256, 0, stream>>>(xbf, 2048, wt_rk, kfull, 2048, 2048, 1, 64);

  rope_kernel<<<(2 * 2048 * 16 * 32) / 256, 256, 0, stream>>>(qfull, kfull);
  attn_kernel<<<dim3(32, 32), 256, 0, stream>>>(qfull, kfull, vfull, ybuf);
  // out = y @ W_o   (fp32 store)
  gemm_bt<<<dim3(16, 32), 256, 0, stream>>>(ybuf, 2048, wt_o, (float*)d_out, 2048, 2048, 0, 0);
}